// Round 25
// baseline (2917.264 us; speedup 1.0000x reference)
//
#include <hip/hip_runtime.h>

#define BB 8
#define TT 16
#define HH 256
#define WW 256
#define HW (HH*WW)            // 65536
#define NPT (BB*HW)           // 524288 points
#define EMPTY_FLOOR 0.012f

// ws (16 MB): st float4[NPT]=8MB | rec Rec[NPT]=6MB | meta u32[NPT]=2MB |
//             rowcnt u32[2][BB][256]=16KB
// Arithmetic VERBATIM R15/R23 (A-init f32 bits; f64 step math, f32 state
// rounding; R6-f32 defused splat weights; empty-cell floor). DO NOT TOUCH.
// R25: row-bucketing replaces bin-sorting. Per step: k_scat (rbase scan +
// row-ordered rec write, atomic-free) -> k_gathadv (256x2 tile streams 3
// contiguous row buckets into LDS; then adv(t+1)). No scan kernel, no hist.

struct Rec { float sx, sy, nR; };

__device__ __forceinline__ float fmul_sr(float a, float b) {
    float r = a * b;
    __asm__("" : "+v"(r));
    return r;
}

// ---- R15-verbatim advection core; row-bucket count + (row,rank) meta ----
__device__ __forceinline__ void adv_core(const float* __restrict__ dec,
                                         float4& s,
                                         unsigned* __restrict__ rowcnt_next,
                                         unsigned* __restrict__ meta,
                                         int idx, int b, int t) {
    const float* U = dec + (size_t)((b * TT + t) * 3) * HW;
    const float* V = U + HW;
    const float* C = U + 2 * HW;

    double X = (double)s.x, Y = (double)s.y, R = (double)s.z;
    double ix = X * 256.0 - 0.5;
    double iy = Y * 256.0 - 0.5;
    double x0 = floor(ix);
    double y0 = floor(iy);

    double gU = 0.0, gV = 0.0, gC = 0.0;
    #pragma unroll
    for (int k = 0; k < 4; ++k) {
        double dxf = (double)(k & 1), dyf = (double)(k >> 1);
        double xc = x0 + dxf, yc = y0 + dyf;
        double w = (1.0 - fabs(ix - xc)) * (1.0 - fabs(iy - yc));
        bool valid = (xc >= 0.0) && (xc < 256.0) && (yc >= 0.0) && (yc < 256.0);
        double wv = valid ? w : 0.0;
        int xi = (int)fmin(fmax(xc, 0.0), 255.0);
        int yi = (int)fmin(fmax(yc, 0.0), 255.0);
        int ii = yi * WW + xi;
        double uT = (((double)U[ii] - 0.5) * 5.0) / 256.0;
        double vT = (((double)V[ii] - 0.5) * 5.0) / 256.0;
        double cT = (double)C[ii];
        gU = gU + uT * wv;
        gV = gV + vT * wv;
        gC = gC + cT * wv;
    }

    double nXd = X + gU; nXd = fmin(fmax(nXd, 0.0), 1.0);
    double nYd = Y + gV; nYd = fmin(fmax(nYd, 0.0), 1.0);
    double nRd = R * gC; nRd = fmin(fmax(nRd, 0.0), 1.0);
    float nX = (float)nXd;
    float nY = (float)nYd;
    float nR = (float)nRd;
    s.x = nX; s.y = nY; s.z = nR;

    float sy = fmul_sr(nY, 255.0f);          // same bits as splat sy
    int row = (int)floorf(sy);               // 0..255
    unsigned rank = atomicAdd(&rowcnt_next[(b << 8) + row], 1u); // < 65536
    meta[idx] = ((unsigned)row << 16) | rank;
}

// wave-shuffle exclusive row-base scan of rowcnt[b][*]
__device__ __forceinline__ void load_rowbases(const unsigned* __restrict__ rc,
                                              int b, unsigned* rbase,
                                              unsigned* rtot) {
    __shared__ unsigned wsum[4];
    int tid  = threadIdx.x;
    int lane = tid & 63, wave = tid >> 6;
    unsigned v = rc[(b << 8) + tid];
    rtot[tid] = v;
    unsigned sc = v;
    #pragma unroll
    for (int d = 1; d < 64; d <<= 1) {
        unsigned u = (unsigned)__shfl_up((int)sc, d);
        if (lane >= d) sc += u;
    }
    if (lane == 63) wsum[wave] = sc;
    __syncthreads();
    unsigned base = 0;
    #pragma unroll
    for (int w = 0; w < 4; ++w) if (w < wave) base += wsum[w];
    rbase[tid] = base + sc - v;              // exclusive
    __syncthreads();
}

// init state + advection of step 0 (rowcnt pre-zeroed by memsetAsync)
__global__ __launch_bounds__(256) void k_initadv(
        const float* __restrict__ x, const float* __restrict__ dec,
        float4* __restrict__ st, unsigned* __restrict__ meta,
        unsigned* __restrict__ rowcnt0) {
#pragma clang fp contract(off)
    int b   = blockIdx.x & 7;
    int sub = blockIdx.x >> 3;
    int p0  = (b << 16) + sub * 512 + threadIdx.x;
    #pragma unroll
    for (int q = 0; q < 2; ++q) {
        int idx = p0 + q * 256;
        int p  = idx & (HW - 1);
        int px = p & (WW - 1);
        int py = p >> 8;
        float4 s;
        s.x = (float)px * (1.0f / 255.0f);   // A-init bits (proven basin)
        s.y = (float)py * (1.0f / 255.0f);
        s.z = x[(size_t)(b * TT + (TT - 1)) * HW + p];
        s.w = 0.0f;
        adv_core(dec, s, rowcnt0, meta, idx, b, 0);
        st[idx] = s;
    }
}

// atomic-free row-ordered scatter; also zeroes next-parity rowcnt
__global__ __launch_bounds__(256) void k_scat(const float4* __restrict__ st,
                                              const unsigned* __restrict__ meta,
                                              Rec* __restrict__ rec,
                                              const unsigned* __restrict__ rowcnt_cur,
                                              unsigned* __restrict__ rowcnt_next) {
#pragma clang fp contract(off)
    __shared__ unsigned rbase[256];
    __shared__ unsigned rtot[256];
    int b   = blockIdx.x & 7;
    int sub = blockIdx.x >> 3;
    int tid = threadIdx.x;
    if (sub == 0) rowcnt_next[(b << 8) + tid] = 0u;   // ready for adv(t+1)
    load_rowbases(rowcnt_cur, b, rbase, rtot);

    int p0 = (b << 16) + sub * 512 + tid;
    #pragma unroll
    for (int q = 0; q < 2; ++q) {
        int idx = p0 + q * 256;
        float4 s = st[idx];
        unsigned m = meta[idx];
        unsigned row = m >> 16, rank = m & 0xFFFFu;
        unsigned slot = rbase[row] + rank;
        Rec r;
        r.sx = fmul_sr(s.x, 255.0f);   // same bits as splat sx
        r.sy = fmul_sr(s.y, 255.0f);
        r.nR = s.z;
        rec[((size_t)b << 16) + slot] = r;
    }
}

// 256x2 tile gather (3 contiguous row buckets) + advection of step t+1
__global__ __launch_bounds__(256) void k_gathadv(
        const Rec* __restrict__ rec, float* __restrict__ out,
        const float* __restrict__ dec, float4* __restrict__ st,
        unsigned* __restrict__ meta,
        const unsigned* __restrict__ rowcnt_cur,
        unsigned* __restrict__ rowcnt_next, int t) {
#pragma clang fp contract(off)
    __shared__ unsigned rbase[256];
    __shared__ unsigned rtot[256];
    __shared__ float a_lds[2][256];
    __shared__ float w_lds[2][256];

    int b    = blockIdx.x & 7;
    int tile = blockIdx.x >> 3;          // 0..127
    int y0   = tile * 2;                 // tile rows y0, y0+1
    int tid  = threadIdx.x;

    load_rowbases(rowcnt_cur, b, rbase, rtot);
    a_lds[0][tid] = 0.0f; a_lds[1][tid] = 0.0f;
    w_lds[0][tid] = 0.0f; w_lds[1][tid] = 0.0f;
    __syncthreads();

    const Rec* rb = rec + ((size_t)b << 16);
    int byLo = (y0 == 0) ? 0 : y0 - 1;
    unsigned span0 = rbase[byLo];
    unsigned span1 = rbase[y0 + 1] + rtot[y0 + 1];   // y0+1 <= 255

    for (unsigned i = span0 + tid; i < span1; i += 256) {
        Rec rr = rb[i];
        float sx0f = floorf(rr.sx), sy0f = floorf(rr.sy);
        #pragma unroll
        for (int k = 0; k < 4; ++k) {
            float dxf = (float)(k & 1), dyf = (float)(k >> 1);
            float xc = sx0f + dxf, yc = sy0f + dyf;     // exact
            int cy = (int)yc, cx = (int)xc;
            // row test selects this tile's 2 rows (and enforces yc<=255);
            // cx<=255 enforces xc validity; xc,yc >= 0 always here.
            if (cy >= y0 && cy <= y0 + 1 && cx <= 255) {
                float w = fmul_sr(1.0f - fabsf(rr.sx - xc),
                                  1.0f - fabsf(rr.sy - yc));
                if (w != 0.0f) {                        // matches splat skip
                    atomicAdd(&a_lds[cy - y0][cx], fmul_sr(rr.nR, w));
                    atomicAdd(&w_lds[cy - y0][cx], w);
                }
            }
        }
    }
    __syncthreads();

    size_t obase = (size_t)(b * TT + t) * HW + (size_t)y0 * 256;
    #pragma unroll
    for (int r = 0; r < 2; ++r) {
        float a = a_lds[r][tid];
        float w = w_lds[r][tid];
        out[obase + (size_t)r * 256 + tid] =
            (w == 0.0f) ? EMPTY_FLOOR : a / fmaxf(w, 1e-8f);
    }

    // ---- fused advection of step t+1 ----
    int tA = t + 1;
    if (tA < TT) {
        int p0 = (b << 16) + tile * 512 + tid;
        #pragma unroll
        for (int q = 0; q < 2; ++q) {
            int idx = p0 + q * 256;
            float4 s = st[idx];
            adv_core(dec, s, rowcnt_next, meta, idx, b, tA);
            st[idx] = s;
        }
    }
}

extern "C" void kernel_launch(void* const* d_in, const int* in_sizes, int n_in,
                              void* d_out, int out_size, void* d_ws, size_t ws_size,
                              hipStream_t stream) {
    const float* x   = (const float*)d_in[0];
    const float* dec = (const float*)d_in[1];
    float* out = (float*)d_out;

    float4*   st     = (float4*)d_ws;                                       // 8 MB
    Rec*      rec    = (Rec*)(st + (size_t)NPT);                            // 6 MB
    unsigned* meta   = (unsigned*)((char*)rec + (size_t)NPT * sizeof(Rec)); // 2 MB
    unsigned* rowcnt = meta + (size_t)NPT;                                  // 16 KB

    hipMemsetAsync(rowcnt, 0, 2 * BB * 256 * sizeof(unsigned), stream);
    k_initadv<<<1024, 256, 0, stream>>>(x, dec, st, meta, rowcnt);
    for (int t = 0; t < TT; ++t) {
        unsigned* cur  = rowcnt + (size_t)(t & 1) * (BB * 256);
        unsigned* next = rowcnt + (size_t)((t + 1) & 1) * (BB * 256);
        k_scat<<<1024, 256, 0, stream>>>(st, meta, rec, cur, next);
        k_gathadv<<<1024, 256, 0, stream>>>(rec, out, dec, st, meta, cur, next, t);
    }
}

// Round 26
// 546.235 us; speedup vs baseline: 5.3407x; 5.3407x over previous
//
#include <hip/hip_runtime.h>

#define BB 8
#define TT 16
#define HH 256
#define WW 256
#define HW (HH*WW)            // 65536
#define NPT (BB*HW)           // 524288 points
#define EMPTY_FLOOR 0.012f

// ws (16 MB): st float4[NPT]=8MB | rec Rec[NPT]=6MB | meta u32[NPT]=2MB |
//             rowcnt u32[2][BB][256]=16KB
// Arithmetic VERBATIM R15 (A-init f32 bits; f64 step math, f32 state
// rounding; R6-f32 defused splat weights; empty-cell floor). DO NOT TOUCH.
// R26 = R25's 2-dispatch step with contention-free two-level row counting:
// LDS row histogram per block + ONE device atomicAdd per (block,row).
// (R25's per-point atomics onto 256 counters serialized ~256-deep and cost
//  ~170 us/kernel; this removes that while keeping the proven gather.)

struct Rec { float sx, sy, nR; };

__device__ __forceinline__ float fmul_sr(float a, float b) {
    float r = a * b;
    __asm__("" : "+v"(r));
    return r;
}

// ---- R15-verbatim advection math; returns splat row (0..255) ----
__device__ __forceinline__ int adv_math(const float* __restrict__ dec,
                                        float4& s, int b, int t) {
    const float* U = dec + (size_t)((b * TT + t) * 3) * HW;
    const float* V = U + HW;
    const float* C = U + 2 * HW;

    double X = (double)s.x, Y = (double)s.y, R = (double)s.z;
    double ix = X * 256.0 - 0.5;
    double iy = Y * 256.0 - 0.5;
    double x0 = floor(ix);
    double y0 = floor(iy);

    double gU = 0.0, gV = 0.0, gC = 0.0;
    #pragma unroll
    for (int k = 0; k < 4; ++k) {
        double dxf = (double)(k & 1), dyf = (double)(k >> 1);
        double xc = x0 + dxf, yc = y0 + dyf;
        double w = (1.0 - fabs(ix - xc)) * (1.0 - fabs(iy - yc));
        bool valid = (xc >= 0.0) && (xc < 256.0) && (yc >= 0.0) && (yc < 256.0);
        double wv = valid ? w : 0.0;
        int xi = (int)fmin(fmax(xc, 0.0), 255.0);
        int yi = (int)fmin(fmax(yc, 0.0), 255.0);
        int ii = yi * WW + xi;
        double uT = (((double)U[ii] - 0.5) * 5.0) / 256.0;
        double vT = (((double)V[ii] - 0.5) * 5.0) / 256.0;
        double cT = (double)C[ii];
        gU = gU + uT * wv;
        gV = gV + vT * wv;
        gC = gC + cT * wv;
    }

    double nXd = X + gU; nXd = fmin(fmax(nXd, 0.0), 1.0);
    double nYd = Y + gV; nYd = fmin(fmax(nYd, 0.0), 1.0);
    double nRd = R * gC; nRd = fmin(fmax(nRd, 0.0), 1.0);
    float nX = (float)nXd;
    float nY = (float)nYd;
    float nR = (float)nRd;
    s.x = nX; s.y = nY; s.z = nR;

    float sy = fmul_sr(nY, 255.0f);          // same bits as splat sy
    return (int)floorf(sy);                  // 0..255
}

// wave-shuffle exclusive row-base scan of rowcnt[b][*]
__device__ __forceinline__ void load_rowbases(const unsigned* __restrict__ rc,
                                              int b, unsigned* rbase,
                                              unsigned* rtot) {
    __shared__ unsigned wsum[4];
    int tid  = threadIdx.x;
    int lane = tid & 63, wave = tid >> 6;
    unsigned v = rc[(b << 8) + tid];
    rtot[tid] = v;
    unsigned sc = v;
    #pragma unroll
    for (int d = 1; d < 64; d <<= 1) {
        unsigned u = (unsigned)__shfl_up((int)sc, d);
        if (lane >= d) sc += u;
    }
    if (lane == 63) wsum[wave] = sc;
    __syncthreads();
    unsigned base = 0;
    #pragma unroll
    for (int w = 0; w < 4; ++w) if (w < wave) base += wsum[w];
    rbase[tid] = base + sc - v;              // exclusive
    __syncthreads();
}

// init state + advection of step 0 with block-aggregated row counting
__global__ __launch_bounds__(256) void k_initadv(
        const float* __restrict__ x, const float* __restrict__ dec,
        float4* __restrict__ st, unsigned* __restrict__ meta,
        unsigned* __restrict__ rowcnt0) {
#pragma clang fp contract(off)
    __shared__ unsigned cnt[256];
    __shared__ unsigned cbase[256];
    int b   = blockIdx.x & 7;
    int sub = blockIdx.x >> 3;
    int tid = threadIdx.x;
    cnt[tid] = 0u;
    __syncthreads();

    int p0 = (b << 16) + sub * 512 + tid;
    float4 s0, s1;
    int r0, r1;
    unsigned lr0, lr1;
    {
        int idx = p0;
        int p  = idx & (HW - 1);
        s0.x = (float)(p & 255) * (1.0f / 255.0f);   // A-init bits
        s0.y = (float)(p >> 8) * (1.0f / 255.0f);
        s0.z = x[(size_t)(b * TT + (TT - 1)) * HW + p];
        s0.w = 0.0f;
        r0 = adv_math(dec, s0, b, 0);
        lr0 = atomicAdd(&cnt[r0], 1u);
    }
    {
        int idx = p0 + 256;
        int p  = idx & (HW - 1);
        s1.x = (float)(p & 255) * (1.0f / 255.0f);
        s1.y = (float)(p >> 8) * (1.0f / 255.0f);
        s1.z = x[(size_t)(b * TT + (TT - 1)) * HW + p];
        s1.w = 0.0f;
        r1 = adv_math(dec, s1, b, 0);
        lr1 = atomicAdd(&cnt[r1], 1u);
    }
    __syncthreads();
    cbase[tid] = cnt[tid] ? atomicAdd(&rowcnt0[(b << 8) + tid], cnt[tid]) : 0u;
    __syncthreads();
    meta[p0]       = ((unsigned)r0 << 16) | (cbase[r0] + lr0);
    meta[p0 + 256] = ((unsigned)r1 << 16) | (cbase[r1] + lr1);
    st[p0]       = s0;
    st[p0 + 256] = s1;
}

// atomic-free row-ordered scatter; zeroes next-parity rowcnt
__global__ __launch_bounds__(256) void k_scat(const float4* __restrict__ st,
                                              const unsigned* __restrict__ meta,
                                              Rec* __restrict__ rec,
                                              const unsigned* __restrict__ rowcnt_cur,
                                              unsigned* __restrict__ rowcnt_next) {
#pragma clang fp contract(off)
    __shared__ unsigned rbase[256];
    __shared__ unsigned rtot[256];
    int b   = blockIdx.x & 7;
    int sub = blockIdx.x >> 3;
    int tid = threadIdx.x;
    if (sub == 0) rowcnt_next[(b << 8) + tid] = 0u;   // ready for adv(t+1)
    load_rowbases(rowcnt_cur, b, rbase, rtot);

    int p0 = (b << 16) + sub * 512 + tid;
    #pragma unroll
    for (int q = 0; q < 2; ++q) {
        int idx = p0 + q * 256;
        float4 s = st[idx];
        unsigned m = meta[idx];
        unsigned row = m >> 16, rank = m & 0xFFFFu;
        unsigned slot = rbase[row] + rank;
        Rec r;
        r.sx = fmul_sr(s.x, 255.0f);   // same bits as splat sx
        r.sy = fmul_sr(s.y, 255.0f);
        r.nR = s.z;
        rec[((size_t)b << 16) + slot] = r;
    }
}

// 256x2 tile gather (3 contiguous row buckets, R25-proven) + adv(t+1)
__global__ __launch_bounds__(256) void k_gathadv(
        const Rec* __restrict__ rec, float* __restrict__ out,
        const float* __restrict__ dec, float4* __restrict__ st,
        unsigned* __restrict__ meta,
        const unsigned* __restrict__ rowcnt_cur,
        unsigned* __restrict__ rowcnt_next, int t) {
#pragma clang fp contract(off)
    __shared__ unsigned rbase[256];
    __shared__ unsigned rtot[256];
    __shared__ float a_lds[2][256];
    __shared__ float w_lds[2][256];
    __shared__ unsigned cnt[256];
    __shared__ unsigned cbase[256];

    int b    = blockIdx.x & 7;
    int tile = blockIdx.x >> 3;          // 0..127
    int y0   = tile * 2;
    int tid  = threadIdx.x;

    load_rowbases(rowcnt_cur, b, rbase, rtot);
    a_lds[0][tid] = 0.0f; a_lds[1][tid] = 0.0f;
    w_lds[0][tid] = 0.0f; w_lds[1][tid] = 0.0f;
    cnt[tid] = 0u;
    __syncthreads();

    const Rec* rb = rec + ((size_t)b << 16);
    int byLo = (y0 == 0) ? 0 : y0 - 1;
    unsigned span0 = rbase[byLo];
    unsigned span1 = rbase[y0 + 1] + rtot[y0 + 1];   // y0+1 <= 255

    for (unsigned i = span0 + tid; i < span1; i += 256) {
        Rec rr = rb[i];
        float sx0f = floorf(rr.sx), sy0f = floorf(rr.sy);
        #pragma unroll
        for (int k = 0; k < 4; ++k) {
            float dxf = (float)(k & 1), dyf = (float)(k >> 1);
            float xc = sx0f + dxf, yc = sy0f + dyf;     // exact
            int cy = (int)yc, cx = (int)xc;
            if (cy >= y0 && cy <= y0 + 1 && cx <= 255) {
                float w = fmul_sr(1.0f - fabsf(rr.sx - xc),
                                  1.0f - fabsf(rr.sy - yc));
                if (w != 0.0f) {                        // matches splat skip
                    atomicAdd(&a_lds[cy - y0][cx], fmul_sr(rr.nR, w));
                    atomicAdd(&w_lds[cy - y0][cx], w);
                }
            }
        }
    }
    __syncthreads();

    size_t obase = (size_t)(b * TT + t) * HW + (size_t)y0 * 256;
    #pragma unroll
    for (int r = 0; r < 2; ++r) {
        float a = a_lds[r][tid];
        float w = w_lds[r][tid];
        out[obase + (size_t)r * 256 + tid] =
            (w == 0.0f) ? EMPTY_FLOOR : a / fmaxf(w, 1e-8f);
    }

    // ---- fused advection of step t+1, block-aggregated row counting ----
    int tA = t + 1;
    if (tA < TT) {
        int p0 = (b << 16) + tile * 512 + tid;
        float4 s0 = st[p0], s1 = st[p0 + 256];
        int r0 = adv_math(dec, s0, b, tA);
        unsigned lr0 = atomicAdd(&cnt[r0], 1u);
        int r1 = adv_math(dec, s1, b, tA);
        unsigned lr1 = atomicAdd(&cnt[r1], 1u);
        __syncthreads();
        cbase[tid] = cnt[tid] ? atomicAdd(&rowcnt_next[(b << 8) + tid], cnt[tid]) : 0u;
        __syncthreads();
        meta[p0]       = ((unsigned)r0 << 16) | (cbase[r0] + lr0);
        meta[p0 + 256] = ((unsigned)r1 << 16) | (cbase[r1] + lr1);
        st[p0]       = s0;
        st[p0 + 256] = s1;
    }
}

extern "C" void kernel_launch(void* const* d_in, const int* in_sizes, int n_in,
                              void* d_out, int out_size, void* d_ws, size_t ws_size,
                              hipStream_t stream) {
    const float* x   = (const float*)d_in[0];
    const float* dec = (const float*)d_in[1];
    float* out = (float*)d_out;

    float4*   st     = (float4*)d_ws;                                       // 8 MB
    Rec*      rec    = (Rec*)(st + (size_t)NPT);                            // 6 MB
    unsigned* meta   = (unsigned*)((char*)rec + (size_t)NPT * sizeof(Rec)); // 2 MB
    unsigned* rowcnt = meta + (size_t)NPT;                                  // 16 KB

    hipMemsetAsync(rowcnt, 0, 2 * BB * 256 * sizeof(unsigned), stream);
    k_initadv<<<1024, 256, 0, stream>>>(x, dec, st, meta, rowcnt);
    for (int t = 0; t < TT; ++t) {
        unsigned* cur  = rowcnt + (size_t)(t & 1) * (BB * 256);
        unsigned* next = rowcnt + (size_t)((t + 1) & 1) * (BB * 256);
        k_scat<<<1024, 256, 0, stream>>>(st, meta, rec, cur, next);
        k_gathadv<<<1024, 256, 0, stream>>>(rec, out, dec, st, meta, cur, next, t);
    }
}

// Round 27
// 518.685 us; speedup vs baseline: 5.6244x; 1.0531x over previous
//
#include <hip/hip_runtime.h>

#define BB 8
#define TT 16
#define HH 256
#define WW 256
#define HW (HH*WW)            // 65536
#define NPT (BB*HW)           // 524288 points
#define EMPTY_FLOOR 0.012f

// ws (20 MB EXACT, R1-proven): st_xy float2[NPT]=4MB | st_r f32[NPT]=2MB |
//   meta u32[NPT]=2MB | rec Rec[2][NPT]=12MB
// rowcnt: __device__ u32[4][BB][256] (32KB), 4-deep rotation, re-zeroed per call.
// Arithmetic VERBATIM R15/R26 (A-init f32 bits; f64 step math, f32 state
// rounding; R6-f32 defused splat weights; empty-cell floor). DO NOT TOUCH.
// R27: one kernel per step: K(j) = { scat(j) | gather(j-1) | adv(j+1) }.
// Cross-step deps all resolve at kernel boundaries; per-block phases touch
// only the block's own st/meta entries (no intra-dispatch cross-block race).

struct Rec { float sx, sy, nR; };

__device__ unsigned g_rowcnt[4][BB][256];

__device__ __forceinline__ float fmul_sr(float a, float b) {
    float r = a * b;
    __asm__("" : "+v"(r));
    return r;
}

// ---- R15-verbatim advection math (split state); returns splat row ----
__device__ __forceinline__ int adv_math(const float* __restrict__ dec,
                                        float2& xy, float& rval, int b, int t) {
    const float* U = dec + (size_t)((b * TT + t) * 3) * HW;
    const float* V = U + HW;
    const float* C = U + 2 * HW;

    double X = (double)xy.x, Y = (double)xy.y, R = (double)rval;
    double ix = X * 256.0 - 0.5;
    double iy = Y * 256.0 - 0.5;
    double x0 = floor(ix);
    double y0 = floor(iy);

    double gU = 0.0, gV = 0.0, gC = 0.0;
    #pragma unroll
    for (int k = 0; k < 4; ++k) {
        double dxf = (double)(k & 1), dyf = (double)(k >> 1);
        double xc = x0 + dxf, yc = y0 + dyf;
        double w = (1.0 - fabs(ix - xc)) * (1.0 - fabs(iy - yc));
        bool valid = (xc >= 0.0) && (xc < 256.0) && (yc >= 0.0) && (yc < 256.0);
        double wv = valid ? w : 0.0;
        int xi = (int)fmin(fmax(xc, 0.0), 255.0);
        int yi = (int)fmin(fmax(yc, 0.0), 255.0);
        int ii = yi * WW + xi;
        double uT = (((double)U[ii] - 0.5) * 5.0) / 256.0;
        double vT = (((double)V[ii] - 0.5) * 5.0) / 256.0;
        double cT = (double)C[ii];
        gU = gU + uT * wv;
        gV = gV + vT * wv;
        gC = gC + cT * wv;
    }

    double nXd = X + gU; nXd = fmin(fmax(nXd, 0.0), 1.0);
    double nYd = Y + gV; nYd = fmin(fmax(nYd, 0.0), 1.0);
    double nRd = R * gC; nRd = fmin(fmax(nRd, 0.0), 1.0);
    float nX = (float)nXd;
    float nY = (float)nYd;
    float nR = (float)nRd;
    xy.x = nX; xy.y = nY; rval = nR;

    float sy = fmul_sr(nY, 255.0f);          // same bits as splat sy
    return (int)floorf(sy);                  // 0..255
}

// wave-shuffle exclusive row-base scan of a 256-entry count array
__device__ __forceinline__ void load_rowbases(const unsigned* __restrict__ rc,
                                              unsigned* rbase, unsigned* rtot) {
    __shared__ unsigned wsum[4];
    int tid  = threadIdx.x;
    int lane = tid & 63, wave = tid >> 6;
    unsigned v = rc[tid];
    rtot[tid] = v;
    unsigned sc = v;
    #pragma unroll
    for (int d = 1; d < 64; d <<= 1) {
        unsigned u = (unsigned)__shfl_up((int)sc, d);
        if (lane >= d) sc += u;
    }
    if (lane == 63) wsum[wave] = sc;
    __syncthreads();
    unsigned base = 0;
    #pragma unroll
    for (int w = 0; w < 4; ++w) if (w < wave) base += wsum[w];
    rbase[tid] = base + sc - v;              // exclusive
    __syncthreads();
}

__global__ void k_zero() {
    int i = blockIdx.x * blockDim.x + threadIdx.x;
    if (i < 4 * BB * 256) ((unsigned*)g_rowcnt)[i] = 0u;
}

// init state + adv(0) with block-aggregated row counting into buf[0]
__global__ __launch_bounds__(256) void k_initadv(
        const float* __restrict__ x, const float* __restrict__ dec,
        float2* __restrict__ st_xy, float* __restrict__ st_r,
        unsigned* __restrict__ meta) {
#pragma clang fp contract(off)
    __shared__ unsigned cnt[256];
    __shared__ unsigned cbase[256];
    int b    = blockIdx.x & 7;
    int tile = blockIdx.x >> 3;
    int tid  = threadIdx.x;
    cnt[tid] = 0u;
    __syncthreads();

    int p0 = (b << 16) + tile * 512 + tid;
    float2 xy0, xy1; float r0v, r1v;
    int r0, r1; unsigned lr0, lr1;
    {
        int p = p0 & (HW - 1);
        xy0.x = (float)(p & 255) * (1.0f / 255.0f);   // A-init bits
        xy0.y = (float)(p >> 8) * (1.0f / 255.0f);
        r0v = x[(size_t)(b * TT + (TT - 1)) * HW + p];
        r0 = adv_math(dec, xy0, r0v, b, 0);
        lr0 = atomicAdd(&cnt[r0], 1u);
    }
    {
        int p = (p0 + 256) & (HW - 1);
        xy1.x = (float)(p & 255) * (1.0f / 255.0f);
        xy1.y = (float)(p >> 8) * (1.0f / 255.0f);
        r1v = x[(size_t)(b * TT + (TT - 1)) * HW + p];
        r1 = adv_math(dec, xy1, r1v, b, 0);
        lr1 = atomicAdd(&cnt[r1], 1u);
    }
    __syncthreads();
    cbase[tid] = cnt[tid] ? atomicAdd(&g_rowcnt[0][b][tid], cnt[tid]) : 0u;
    __syncthreads();
    meta[p0]       = ((unsigned)r0 << 16) | (cbase[r0] + lr0);
    meta[p0 + 256] = ((unsigned)r1 << 16) | (cbase[r1] + lr1);
    st_xy[p0] = xy0;       st_r[p0] = r0v;
    st_xy[p0 + 256] = xy1; st_r[p0 + 256] = r1v;
}

// K(j): scat(j) [j<=15] | gather(j-1) [j>=1] | adv(j+1) [j<=14]
__global__ __launch_bounds__(256) void k_step(
        float2* __restrict__ st_xy, float* __restrict__ st_r,
        unsigned* __restrict__ meta, Rec* __restrict__ rec,
        float* __restrict__ out, const float* __restrict__ dec, int j) {
#pragma clang fp contract(off)
    __shared__ unsigned rbaseA[256], rtotA[256];
    __shared__ unsigned rbaseG[256], rtotG[256];
    __shared__ float a_lds[2][256], w_lds[2][256];
    __shared__ unsigned cnt[256], cbase[256];

    int b    = blockIdx.x & 7;
    int tile = blockIdx.x >> 3;          // 0..127
    int tid  = threadIdx.x;
    int p0   = (b << 16) + tile * 512 + tid;

    // zero rowcnt buf[(j+2)&3] for adv(j+2) in K(j+1); untouched in K(j)
    {
        unsigned* z = &g_rowcnt[(j + 2) & 3][0][0];
        z[blockIdx.x * 2]     = 0u;
        z[blockIdx.x * 2 + 1] = 0u;
    }

    // ---- phase A: scat(j) ----
    if (j <= 15) {
        load_rowbases(&g_rowcnt[j & 3][b][0], rbaseA, rtotA);
        Rec* rw = rec + (size_t)(j & 1) * NPT + ((size_t)b << 16);
        #pragma unroll
        for (int q = 0; q < 2; ++q) {
            int idx = p0 + q * 256;
            float2 xy = st_xy[idx];
            float  rv = st_r[idx];
            unsigned m = meta[idx];
            unsigned row = m >> 16, rank = m & 0xFFFFu;
            Rec r;
            r.sx = fmul_sr(xy.x, 255.0f);   // same bits as splat sx
            r.sy = fmul_sr(xy.y, 255.0f);
            r.nR = rv;
            rw[rbaseA[row] + rank] = r;
        }
    }

    // ---- phase B: gather(j-1) (R25/R26-proven body) ----
    if (j >= 1) {
        load_rowbases(&g_rowcnt[(j - 1) & 3][b][0], rbaseG, rtotG);
        a_lds[0][tid] = 0.0f; a_lds[1][tid] = 0.0f;
        w_lds[0][tid] = 0.0f; w_lds[1][tid] = 0.0f;
        __syncthreads();

        const Rec* rb = rec + (size_t)((j - 1) & 1) * NPT + ((size_t)b << 16);
        int y0 = tile * 2;
        int byLo = (y0 == 0) ? 0 : y0 - 1;
        unsigned span0 = rbaseG[byLo];
        unsigned span1 = rbaseG[y0 + 1] + rtotG[y0 + 1];   // y0+1 <= 255

        for (unsigned i = span0 + tid; i < span1; i += 256) {
            Rec rr = rb[i];
            float sx0f = floorf(rr.sx), sy0f = floorf(rr.sy);
            #pragma unroll
            for (int k = 0; k < 4; ++k) {
                float dxf = (float)(k & 1), dyf = (float)(k >> 1);
                float xc = sx0f + dxf, yc = sy0f + dyf;     // exact
                int cy = (int)yc, cx = (int)xc;
                if (cy >= y0 && cy <= y0 + 1 && cx <= 255) {
                    float w = fmul_sr(1.0f - fabsf(rr.sx - xc),
                                      1.0f - fabsf(rr.sy - yc));
                    if (w != 0.0f) {                        // matches splat skip
                        atomicAdd(&a_lds[cy - y0][cx], fmul_sr(rr.nR, w));
                        atomicAdd(&w_lds[cy - y0][cx], w);
                    }
                }
            }
        }
        __syncthreads();

        size_t obase = (size_t)(b * TT + (j - 1)) * HW + (size_t)y0 * 256;
        #pragma unroll
        for (int r = 0; r < 2; ++r) {
            float a = a_lds[r][tid];
            float w = w_lds[r][tid];
            out[obase + (size_t)r * 256 + tid] =
                (w == 0.0f) ? EMPTY_FLOOR : a / fmaxf(w, 1e-8f);
        }
    }

    // ---- phase C: adv(j+1), block-aggregated row counting ----
    if (j + 1 <= 15) {
        cnt[tid] = 0u;
        __syncthreads();
        float2 xy0 = st_xy[p0],       xy1 = st_xy[p0 + 256];
        float  r0v = st_r[p0],        r1v = st_r[p0 + 256];
        int r0 = adv_math(dec, xy0, r0v, b, j + 1);
        unsigned lr0 = atomicAdd(&cnt[r0], 1u);
        int r1 = adv_math(dec, xy1, r1v, b, j + 1);
        unsigned lr1 = atomicAdd(&cnt[r1], 1u);
        __syncthreads();
        cbase[tid] = cnt[tid]
                   ? atomicAdd(&g_rowcnt[(j + 1) & 3][b][tid], cnt[tid]) : 0u;
        __syncthreads();
        meta[p0]       = ((unsigned)r0 << 16) | (cbase[r0] + lr0);
        meta[p0 + 256] = ((unsigned)r1 << 16) | (cbase[r1] + lr1);
        st_xy[p0] = xy0;       st_r[p0] = r0v;
        st_xy[p0 + 256] = xy1; st_r[p0 + 256] = r1v;
    }
}

extern "C" void kernel_launch(void* const* d_in, const int* in_sizes, int n_in,
                              void* d_out, int out_size, void* d_ws, size_t ws_size,
                              hipStream_t stream) {
    const float* x   = (const float*)d_in[0];
    const float* dec = (const float*)d_in[1];
    float* out = (float*)d_out;

    float2*   st_xy = (float2*)d_ws;                            // 4 MB
    float*    st_r  = (float*)(st_xy + (size_t)NPT);            // 2 MB
    unsigned* meta  = (unsigned*)(st_r + (size_t)NPT);          // 2 MB
    Rec*      rec   = (Rec*)(meta + (size_t)NPT);               // 12 MB -> 20 MB

    k_zero<<<32, 256, 0, stream>>>();
    k_initadv<<<1024, 256, 0, stream>>>(x, dec, st_xy, st_r, meta);
    for (int j = 0; j <= TT; ++j) {
        k_step<<<1024, 256, 0, stream>>>(st_xy, st_r, meta, rec, out, dec, j);
    }
}